// Round 17
// baseline (81.877 us; speedup 1.0000x reference)
//
#include <hip/hip_runtime.h>
#include <stdint.h>

#define BB 4
#define NN 2000
#define K_PRE 1000
#define KPAD 1024
#define MAXOUT 128
#define NMS_THR 0.3f
#define MASK_IN_VOX (28*28*28)   // 21952
#define MASK_OUT_VOX (32*32*32)  // 32768

typedef float f4 __attribute__((ext_vector_type(4)));   // nontemporal-compatible

// ---------------- rank (stable descending argsort) + regression -------------
__global__ __launch_bounds__(256) void rank_kernel(const float* __restrict__ scores,
                                                   const float* __restrict__ proposals,
                                                   const float* __restrict__ deltas,
                                                   int* __restrict__ order,
                                                   float* __restrict__ boxes_ws) {
    int b = blockIdx.x >> 5;
    int blk = blockIdx.x & 31;
    __shared__ float s[NN];
    const float* sb = scores + b * NN;
    for (int u = threadIdx.x; u < NN / 4; u += 256)
        ((float4*)s)[u] = ((const float4*)sb)[u];
    __syncthreads();

    int i = blk * 64 + (threadIdx.x >> 2);
    int q = threadIdx.x & 3;
    float si = (i < NN) ? s[i] : 0.f;
    int cnt = 0;
    int j0 = q * 500;
    const float4* s4 = (const float4*)s;
#pragma unroll 5
    for (int u = 0; u < 125; ++u) {
        float4 v = s4[j0 / 4 + u];
        int j = j0 + u * 4;
        cnt += (v.x > si) + (v.y > si) + (v.z > si) + (v.w > si);
        cnt += ((v.x == si) & (j + 0 < i)) + ((v.y == si) & (j + 1 < i))
             + ((v.z == si) & (j + 2 < i)) + ((v.w == si) & (j + 3 < i));
    }
    cnt += __shfl_xor(cnt, 1);
    cnt += __shfl_xor(cnt, 2);

    if (q == 0 && i < NN && cnt < K_PRE) {
        int rank = cnt;
        order[b * KPAD + rank] = i;
        const float* p = proposals + (size_t)(b * NN + i) * 6;
        const float* d = deltas    + (size_t)(b * NN + i) * 6;
        float py1 = p[0], px1 = p[1], pz1 = p[2], py2 = p[3], px2 = p[4], pz2 = p[5];
        float h = py2 - py1, w = px2 - px1, dd = pz2 - pz1;
        float cy = py1 + 0.5f * h + d[0] * h;
        float cx = px1 + 0.5f * w + d[1] * w;
        float cz = pz1 + 0.5f * dd + d[2] * dd;
        h *= expf(d[3]); w *= expf(d[4]); dd *= expf(d[5]);
        float* bw = boxes_ws + (size_t)b * 6 * KPAD + rank;
        bw[0 * KPAD] = cy - 0.5f * h;  bw[1 * KPAD] = cx - 0.5f * w;  bw[2 * KPAD] = cz - 0.5f * dd;
        bw[3 * KPAD] = cy + 0.5f * h;  bw[4 * KPAD] = cx + 0.5f * w;  bw[5 * KPAD] = cz + 0.5f * dd;
    }
}

// ---------------- suppression bit-matrix build ------------------------------
// rowBits[(b*KPAD+k)*64+l] (uint16): bit w <=> IoU(box k, box 64w+l) > thr
__global__ __launch_bounds__(256) void build_kernel(const float* __restrict__ boxes_ws,
                                                    unsigned short* __restrict__ rowBits) {
    int b = blockIdx.y;
    int kbase = blockIdx.x * 16;
    __shared__ float sbx[6][1088];     // stride-17 padding: index k + (k>>4)
    int tid = threadIdx.x;
    const float* bw = boxes_ws + (size_t)b * 6 * KPAD;
    for (int k = tid; k < KPAD; k += 256) {
        int ks = k + (k >> 4);
#pragma unroll
        for (int c = 0; c < 6; ++c) sbx[c][ks] = bw[c * KPAD + k];
    }
    __syncthreads();
    int l = tid & 63, lr = tid >> 6;
#pragma unroll
    for (int pss = 0; pss < 4; ++pss) {
        int k = kbase + pss * 4 + lr;
        int ks = k + (k >> 4);
        float ry1 = sbx[0][ks], rx1 = sbx[1][ks], rz1 = sbx[2][ks];
        float ry2 = sbx[3][ks], rx2 = sbx[4][ks], rz2 = sbx[5][ks];
        float v1 = (ry2 - ry1) * (rx2 - rx1) * (rz2 - rz1);
        uint32_t bits = 0;
#pragma unroll
        for (int w = 0; w < 16; ++w) {
            int j = 64 * w + l;
            int js = j + (j >> 4);
            float y1 = sbx[0][js], x1 = sbx[1][js], z1 = sbx[2][js];
            float y2 = sbx[3][js], x2 = sbx[4][js], z2 = sbx[5][js];
            float iy = fmaxf(fminf(ry2, y2) - fmaxf(ry1, y1), 0.f);
            float ix = fmaxf(fminf(rx2, x2) - fmaxf(rx1, x1), 0.f);
            float iz = fmaxf(fminf(rz2, z2) - fmaxf(rz1, z1), 0.f);
            float inter = iy * ix * iz;
            float v2 = (y2 - y1) * (x2 - x1) * (z2 - z1);
            float iou = inter / (v1 + v2 - inter + 1e-8f);
            bits |= (iou > NMS_THR ? 1u : 0u) << w;
        }
        if (k < K_PRE)
            rowBits[((size_t)(b * KPAD + k)) * 64 + l] = (unsigned short)bits;
    }
}

// ---------------- fused walk + lane=x shuffle-lerp resize -------------------
__global__ __launch_bounds__(256) void resize_walk_kernel(
        const float* __restrict__ masks,
        const unsigned short* __restrict__ rowBits,
        const int* __restrict__ order,
        const float* __restrict__ boxes_ws,
        float* __restrict__ out_boxes,
        float* __restrict__ out_masks,
        float* __restrict__ out_bidx) {
    int s = blockIdx.x;            // 0..511
    int b = s >> 7;
    int sl = s & 127;              // which pick this block owns
    int tid = threadIdx.x;

    __shared__ int   res_k;
    __shared__ float res_vf;

    // ---- redundant early-exit ballot walk (R12/R16-proven) ----
    if (tid < 64) {
        int lane = tid;
        const unsigned short* rowB = rowBits + (size_t)b * KPAD * 64;
        uint32_t sup = (lane >= 40) ? (1u << 15) : 0u;   // pads >=1000 pre-suppressed
        int nsel = 0, kmine = 0, got = 0;

        auto ROW = [&](int g) -> unsigned short {
            return rowB[((size_t)g << 6) + lane];        // L2 read, 128 B/row
        };

        for (int w = 0; w < 16 && nsel <= sl; ++w) {
            unsigned long long m = ~__ballot((int)((sup >> w) & 1u));
            while (m != 0ull && nsel <= sl) {
                unsigned long long t = m;
                int k1 = __builtin_ctzll(t); t &= t - 1;
                bool h2 = t != 0; int k2 = h2 ? __builtin_ctzll(t) : k1; t &= t - 1;
                bool h3 = t != 0; int k3 = h3 ? __builtin_ctzll(t) : k1; t &= t - 1;
                bool h4 = t != 0; int k4 = h4 ? __builtin_ctzll(t) : k1;
                int g1 = (w << 6) + k1, g2 = (w << 6) + k2;
                int g3 = (w << 6) + k3, g4 = (w << 6) + k4;
                unsigned short r1 = ROW(g1), r2 = ROW(g2), r3 = ROW(g3), r4 = ROW(g4);
                if (nsel == sl) { kmine = g1; got = 1; }
                sup |= r1; nsel++;
                m = ~__ballot((int)((sup >> w) & 1u));
                if (h2 && nsel <= sl && ((m >> k2) & 1ull)) {
                    if (nsel == sl) { kmine = g2; got = 1; }
                    sup |= r2; nsel++;
                    m = ~__ballot((int)((sup >> w) & 1u));
                }
                if (h3 && nsel <= sl && ((m >> k3) & 1ull)) {
                    if (nsel == sl) { kmine = g3; got = 1; }
                    sup |= r3; nsel++;
                    m = ~__ballot((int)((sup >> w) & 1u));
                }
                if (h4 && nsel <= sl && ((m >> k4) & 1ull)) {
                    if (nsel == sl) { kmine = g4; got = 1; }
                    sup |= r4; nsel++;
                    m = ~__ballot((int)((sup >> w) & 1u));
                }
            }
        }
        if (lane == 0) { res_k = kmine; res_vf = got ? 1.f : 0.f; }
    }
    __syncthreads();

    int k = res_k;
    float vf = res_vf;
    int gi = order[b * KPAD + k];

    if (tid == 0) {
        const float* bw = boxes_ws + (size_t)b * 6 * KPAD;
        float* ob = out_boxes + (size_t)s * 6;
#pragma unroll
        for (int c = 0; c < 6; ++c) ob[c] = bw[c * KPAD + k] * vf;
        out_bidx[s] = (float)b;
    }

    // ---- lane=x resize: half-wave owns one (oy,oz) output row of 32 ----
    const float* src = masks + (size_t)(b * NN + gi) * MASK_IN_VOX;
    float* dst = out_masks + (size_t)s * MASK_OUT_VOX;

    int lane = tid & 63;
    int hw = (tid >> 6) * 2 + (lane >> 5);     // half-wave id 0..7
    int ox = lane & 31;
    int xi = ox < 28 ? ox : 27;                // clamped load column (avoid OOB tail)

    // per-lane x taps (constant across all iterations)
    int xf = (ox == 0) ? -1 : (14 * ox - 1) >> 4;
    float fx = (0.875f * (float)ox - 0.0625f) - (float)xf;
    int x0 = xf < 0 ? 0 : xf;
    int x1 = xf + 1 > 27 ? 27 : xf + 1;
    int src0 = (lane & 32) + x0;               // shuffle sources within half-wave
    int src1 = (lane & 32) + x1;

#pragma unroll 4
    for (int it = 0; it < 128; ++it) {
        int pair = it * 8 + hw;                // (oy,oz) pair owned this iteration
        int oy = pair & 31, oz = pair >> 5;

        int yf = (oy == 0) ? -1 : (14 * oy - 1) >> 4;
        float fy = (0.875f * (float)oy - 0.0625f) - (float)yf;
        int y0 = yf < 0 ? 0 : yf;
        int y1 = yf + 1 > 27 ? 27 : yf + 1;

        int zf = (oz == 0) ? -1 : (14 * oz - 1) >> 4;
        float fz = (0.875f * (float)oz - 0.0625f) - (float)zf;
        int z0 = zf < 0 ? 0 : zf;
        int z1 = zf + 1 > 27 ? 27 : zf + 1;

        float w00 = (1.f - fy) * (1.f - fz);
        float w01 = fy * (1.f - fz);
        float w10 = (1.f - fy) * fz;
        float w11 = fy * fz;

        // coalesced: half-wave reads 28 contiguous floats per row
        float a  = src[(z0 * 28 + y0) * 28 + xi];
        float bb = src[(z0 * 28 + y1) * 28 + xi];
        float cc = src[(z1 * 28 + y0) * 28 + xi];
        float dd = src[(z1 * 28 + y1) * 28 + xi];
        float c = a * w00 + bb * w01 + cc * w10 + dd * w11;   // zy-lerped row value

        float c0 = __shfl(c, src0);
        float c1 = __shfl(c, src1);
        float r = (c0 + fx * (c1 - c0)) * vf;

        __builtin_nontemporal_store(r, dst + oz * 1024 + oy * 32 + ox);
    }
}

// ---------------- launch ----------------------------------------------------
extern "C" void kernel_launch(void* const* d_in, const int* in_sizes, int n_in,
                              void* d_out, int out_size, void* d_ws, size_t ws_size,
                              hipStream_t stream) {
    const float* proposals = (const float*)d_in[0];
    const float* scores    = (const float*)d_in[1];
    const float* deltas    = (const float*)d_in[2];
    const float* masks     = (const float*)d_in[3];

    float* out = (float*)d_out;
    float* out_boxes = out;                                              // [512,6]
    float* out_masks = out + (size_t)BB * MAXOUT * 6;                    // [512,32768]
    float* out_bidx  = out + (size_t)BB * MAXOUT * 6 + (size_t)BB * MAXOUT * MASK_OUT_VOX;

    char* ws = (char*)d_ws;
    int*            order    = (int*)(ws);                               // 16 KB
    float*          boxes_ws = (float*)(ws + (20 << 10));                // 96 KB
    unsigned short* rowBits  = (unsigned short*)(ws + (116 << 10));      // 512 KB

    rank_kernel<<<BB * 32, 256, 0, stream>>>(scores, proposals, deltas, order, boxes_ws);
    build_kernel<<<dim3(64, BB), 256, 0, stream>>>(boxes_ws, rowBits);
    resize_walk_kernel<<<BB * MAXOUT, 256, 0, stream>>>(masks, rowBits, order, boxes_ws,
                                                        out_boxes, out_masks, out_bidx);
}

// Round 18
// 64.625 us; speedup vs baseline: 1.2669x; 1.2669x over previous
//
#include <hip/hip_runtime.h>
#include <stdint.h>

#define BB 4
#define NN 2000
#define K_PRE 1000
#define KPAD 1024
#define MAXOUT 128
#define NMS_THR 0.3f
#define MASK_IN_VOX (28*28*28)   // 21952
#define MASK_OUT_VOX (32*32*32)  // 32768

typedef float f4 __attribute__((ext_vector_type(4)));   // nontemporal-compatible

// ---------------- rank (stable descending argsort) + regression -------------
__global__ __launch_bounds__(256) void rank_kernel(const float* __restrict__ scores,
                                                   const float* __restrict__ proposals,
                                                   const float* __restrict__ deltas,
                                                   int* __restrict__ order,
                                                   float* __restrict__ boxes_ws) {
    int b = blockIdx.x >> 5;
    int blk = blockIdx.x & 31;
    __shared__ float s[NN];
    const float* sb = scores + b * NN;
    for (int u = threadIdx.x; u < NN / 4; u += 256)
        ((float4*)s)[u] = ((const float4*)sb)[u];
    __syncthreads();

    int i = blk * 64 + (threadIdx.x >> 2);
    int q = threadIdx.x & 3;
    float si = (i < NN) ? s[i] : 0.f;
    int cnt = 0;
    int j0 = q * 500;
    const float4* s4 = (const float4*)s;
#pragma unroll 5
    for (int u = 0; u < 125; ++u) {
        float4 v = s4[j0 / 4 + u];
        int j = j0 + u * 4;
        cnt += (v.x > si) + (v.y > si) + (v.z > si) + (v.w > si);
        cnt += ((v.x == si) & (j + 0 < i)) + ((v.y == si) & (j + 1 < i))
             + ((v.z == si) & (j + 2 < i)) + ((v.w == si) & (j + 3 < i));
    }
    cnt += __shfl_xor(cnt, 1);
    cnt += __shfl_xor(cnt, 2);

    if (q == 0 && i < NN && cnt < K_PRE) {
        int rank = cnt;
        order[b * KPAD + rank] = i;
        const float* p = proposals + (size_t)(b * NN + i) * 6;
        const float* d = deltas    + (size_t)(b * NN + i) * 6;
        float py1 = p[0], px1 = p[1], pz1 = p[2], py2 = p[3], px2 = p[4], pz2 = p[5];
        float h = py2 - py1, w = px2 - px1, dd = pz2 - pz1;
        float cy = py1 + 0.5f * h + d[0] * h;
        float cx = px1 + 0.5f * w + d[1] * w;
        float cz = pz1 + 0.5f * dd + d[2] * dd;
        h *= expf(d[3]); w *= expf(d[4]); dd *= expf(d[5]);
        float* bw = boxes_ws + (size_t)b * 6 * KPAD + rank;
        bw[0 * KPAD] = cy - 0.5f * h;  bw[1 * KPAD] = cx - 0.5f * w;  bw[2 * KPAD] = cz - 0.5f * dd;
        bw[3 * KPAD] = cy + 0.5f * h;  bw[4 * KPAD] = cx + 0.5f * w;  bw[5 * KPAD] = cz + 0.5f * dd;
    }
}

// ---------------- suppression bit-matrix build ------------------------------
// rowBits[(b*KPAD+k)*64+l] (uint16): bit w <=> IoU(box k, box 64w+l) > thr
__global__ __launch_bounds__(256) void build_kernel(const float* __restrict__ boxes_ws,
                                                    unsigned short* __restrict__ rowBits) {
    int b = blockIdx.y;
    int kbase = blockIdx.x * 16;
    __shared__ float sbx[6][1088];     // stride-17 padding: index k + (k>>4)
    int tid = threadIdx.x;
    const float* bw = boxes_ws + (size_t)b * 6 * KPAD;
    for (int k = tid; k < KPAD; k += 256) {
        int ks = k + (k >> 4);
#pragma unroll
        for (int c = 0; c < 6; ++c) sbx[c][ks] = bw[c * KPAD + k];
    }
    __syncthreads();
    int l = tid & 63, lr = tid >> 6;
#pragma unroll
    for (int pss = 0; pss < 4; ++pss) {
        int k = kbase + pss * 4 + lr;
        int ks = k + (k >> 4);
        float ry1 = sbx[0][ks], rx1 = sbx[1][ks], rz1 = sbx[2][ks];
        float ry2 = sbx[3][ks], rx2 = sbx[4][ks], rz2 = sbx[5][ks];
        float v1 = (ry2 - ry1) * (rx2 - rx1) * (rz2 - rz1);
        uint32_t bits = 0;
#pragma unroll
        for (int w = 0; w < 16; ++w) {
            int j = 64 * w + l;
            int js = j + (j >> 4);
            float y1 = sbx[0][js], x1 = sbx[1][js], z1 = sbx[2][js];
            float y2 = sbx[3][js], x2 = sbx[4][js], z2 = sbx[5][js];
            float iy = fmaxf(fminf(ry2, y2) - fmaxf(ry1, y1), 0.f);
            float ix = fmaxf(fminf(rx2, x2) - fmaxf(rx1, x1), 0.f);
            float iz = fmaxf(fminf(rz2, z2) - fmaxf(rz1, z1), 0.f);
            float inter = iy * ix * iz;
            float v2 = (y2 - y1) * (x2 - x1) * (z2 - z1);
            float iou = inter / (v1 + v2 - inter + 1e-8f);
            bits |= (iou > NMS_THR ? 1u : 0u) << w;
        }
        if (k < K_PRE)
            rowBits[((size_t)(b * KPAD + k)) * 64 + l] = (unsigned short)bits;
    }
}

// ---------------- fused walk + chunk-lane resize ----------------------------
__global__ __launch_bounds__(256) void resize_walk_kernel(
        const float* __restrict__ masks,
        const unsigned short* __restrict__ rowBits,
        const int* __restrict__ order,
        const float* __restrict__ boxes_ws,
        float* __restrict__ out_boxes,
        float* __restrict__ out_masks,
        float* __restrict__ out_bidx) {
    int s = blockIdx.x;            // 0..511
    int b = s >> 7;
    int sl = s & 127;              // which pick this block owns
    int tid = threadIdx.x;

    __shared__ int   res_k;
    __shared__ float res_vf;

    // ---- redundant early-exit ballot walk (R12/R16-proven) ----
    if (tid < 64) {
        int lane = tid;
        const unsigned short* rowB = rowBits + (size_t)b * KPAD * 64;
        uint32_t sup = (lane >= 40) ? (1u << 15) : 0u;   // pads >=1000 pre-suppressed
        int nsel = 0, kmine = 0, got = 0;

        auto ROW = [&](int g) -> unsigned short {
            return rowB[((size_t)g << 6) + lane];        // L2 read, 128 B/row
        };

        for (int w = 0; w < 16 && nsel <= sl; ++w) {
            unsigned long long m = ~__ballot((int)((sup >> w) & 1u));
            while (m != 0ull && nsel <= sl) {
                unsigned long long t = m;
                int k1 = __builtin_ctzll(t); t &= t - 1;
                bool h2 = t != 0; int k2 = h2 ? __builtin_ctzll(t) : k1; t &= t - 1;
                bool h3 = t != 0; int k3 = h3 ? __builtin_ctzll(t) : k1; t &= t - 1;
                bool h4 = t != 0; int k4 = h4 ? __builtin_ctzll(t) : k1;
                int g1 = (w << 6) + k1, g2 = (w << 6) + k2;
                int g3 = (w << 6) + k3, g4 = (w << 6) + k4;
                unsigned short r1 = ROW(g1), r2 = ROW(g2), r3 = ROW(g3), r4 = ROW(g4);
                if (nsel == sl) { kmine = g1; got = 1; }
                sup |= r1; nsel++;
                m = ~__ballot((int)((sup >> w) & 1u));
                if (h2 && nsel <= sl && ((m >> k2) & 1ull)) {
                    if (nsel == sl) { kmine = g2; got = 1; }
                    sup |= r2; nsel++;
                    m = ~__ballot((int)((sup >> w) & 1u));
                }
                if (h3 && nsel <= sl && ((m >> k3) & 1ull)) {
                    if (nsel == sl) { kmine = g3; got = 1; }
                    sup |= r3; nsel++;
                    m = ~__ballot((int)((sup >> w) & 1u));
                }
                if (h4 && nsel <= sl && ((m >> k4) & 1ull)) {
                    if (nsel == sl) { kmine = g4; got = 1; }
                    sup |= r4; nsel++;
                    m = ~__ballot((int)((sup >> w) & 1u));
                }
            }
        }
        if (lane == 0) { res_k = kmine; res_vf = got ? 1.f : 0.f; }
    }
    __syncthreads();

    int k = res_k;
    float vf = res_vf;
    int gi = order[b * KPAD + k];

    if (tid == 0) {
        const float* bw = boxes_ws + (size_t)b * 6 * KPAD;
        float* ob = out_boxes + (size_t)s * 6;
#pragma unroll
        for (int c = 0; c < 6; ++c) ob[c] = bw[c * KPAD + k] * vf;
        out_bidx[s] = (float)b;
    }

    // ---- chunk-lane resize: thread = (oy, ox-quad); loop oz ----
    const float* src = masks + (size_t)(b * NN + gi) * MASK_IN_VOX;
    float* dst = out_masks + (size_t)s * MASK_OUT_VOX;

    int q  = tid & 7;          // ox quad 0..7 (ox = 4q..4q+3)
    int oy = tid >> 3;         // 0..31

    // y taps (loop-invariant)
    int yf = (oy == 0) ? -1 : (14 * oy - 1) >> 4;
    float fy = (0.875f * (float)oy - 0.0625f) - (float)yf;
    int y0 = yf < 0 ? 0 : yf;
    int y1 = yf + 1 > 27 ? 27 : yf + 1;

    // x chunk window for this quad: chunks cA, cB cover all 8 taps (verified)
    int ox0 = q * 4;
    int xf0 = (ox0 == 0) ? -1 : (14 * ox0 - 1) >> 4;
    int x0q = xf0 < 0 ? 0 : xf0;
    int cA = x0q >> 2;
    int cB = cA + 1 > 6 ? 6 : cA + 1;

    // 4x8 x-lerp weight matrix (loop-invariant, static indices)
    float W[4][8];
#pragma unroll
    for (int qq = 0; qq < 4; ++qq) {
        int ox = ox0 + qq;
        int xf = (ox == 0) ? -1 : (14 * ox - 1) >> 4;
        float fx = (0.875f * (float)ox - 0.0625f) - (float)xf;
        int x0 = xf < 0 ? 0 : xf;
        int x1 = xf + 1 > 27 ? 27 : xf + 1;
        int i0 = x0 - (cA << 2), i1 = x1 - (cA << 2);
#pragma unroll
        for (int m = 0; m < 8; ++m)
            W[qq][m] = (m == i0 ? 1.f - fx : 0.f) + (m == i1 ? fx : 0.f);
    }

    // y-lerped windows for slices z0 (W0a,W0b) and z1 (W1a,W1b)
    f4 W0a, W0b, W1a, W1b;
    int z0c = -9, z1c = -9;

    auto YL = [&](int z, f4& wa, f4& wb) {
        const f4* r0 = (const f4*)(src + (z * 28 + y0) * 28);
        const f4* r1 = (const f4*)(src + (z * 28 + y1) * 28);
        f4 a0 = r0[cA], a1 = r0[cB];
        f4 b0 = r1[cA], b1 = r1[cB];
        wa = a0 + fy * (b0 - a0);
        wb = a1 + fy * (b1 - a1);
    };

    for (int oz = 0; oz < 32; ++oz) {
        int zf = (oz == 0) ? -1 : (14 * oz - 1) >> 4;
        float fz = (0.875f * (float)oz - 0.0625f) - (float)zf;
        int z0 = zf < 0 ? 0 : zf;
        int z1 = zf + 1 > 27 ? 27 : zf + 1;

        if (z0 != z0c) {
            if (z0 == z1c) { W0a = W1a; W0b = W1b; }
            else           { YL(z0, W0a, W0b); }
            z0c = z0;
        }
        if (z1 != z1c) { YL(z1, W1a, W1b); z1c = z1; }

        f4 Ca = W0a + fz * (W1a - W0a);
        f4 Cb = W0b + fz * (W1b - W0b);
        float e0 = Ca.x, e1 = Ca.y, e2 = Ca.z, e3 = Ca.w;
        float e4 = Cb.x, e5 = Cb.y, e6 = Cb.z, e7 = Cb.w;

        f4 o;
#pragma unroll
        for (int qq = 0; qq < 4; ++qq) {
            float acc = W[qq][0] * e0 + W[qq][1] * e1 + W[qq][2] * e2 + W[qq][3] * e3
                      + W[qq][4] * e4 + W[qq][5] * e5 + W[qq][6] * e6 + W[qq][7] * e7;
            o[qq] = acc * vf;
        }
        __builtin_nontemporal_store(o, (f4*)(dst + oz * 1024 + oy * 32 + ox0));
    }
}

// ---------------- launch ----------------------------------------------------
extern "C" void kernel_launch(void* const* d_in, const int* in_sizes, int n_in,
                              void* d_out, int out_size, void* d_ws, size_t ws_size,
                              hipStream_t stream) {
    const float* proposals = (const float*)d_in[0];
    const float* scores    = (const float*)d_in[1];
    const float* deltas    = (const float*)d_in[2];
    const float* masks     = (const float*)d_in[3];

    float* out = (float*)d_out;
    float* out_boxes = out;                                              // [512,6]
    float* out_masks = out + (size_t)BB * MAXOUT * 6;                    // [512,32768]
    float* out_bidx  = out + (size_t)BB * MAXOUT * 6 + (size_t)BB * MAXOUT * MASK_OUT_VOX;

    char* ws = (char*)d_ws;
    int*            order    = (int*)(ws);                               // 16 KB
    float*          boxes_ws = (float*)(ws + (20 << 10));                // 96 KB
    unsigned short* rowBits  = (unsigned short*)(ws + (116 << 10));      // 512 KB

    rank_kernel<<<BB * 32, 256, 0, stream>>>(scores, proposals, deltas, order, boxes_ws);
    build_kernel<<<dim3(64, BB), 256, 0, stream>>>(boxes_ws, rowBits);
    resize_walk_kernel<<<BB * MAXOUT, 256, 0, stream>>>(masks, rowBits, order, boxes_ws,
                                                        out_boxes, out_masks, out_bidx);
}

// Round 19
// 64.038 us; speedup vs baseline: 1.2786x; 1.0092x over previous
//
#include <hip/hip_runtime.h>
#include <stdint.h>

#define BB 4
#define NN 2000
#define K_PRE 1000
#define KPAD 1024
#define MAXOUT 128
#define NMS_THR 0.3f
#define MASK_IN_VOX (28*28*28)   // 21952
#define MASK_OUT_VOX (32*32*32)  // 32768

typedef float f4 __attribute__((ext_vector_type(4)));   // nontemporal-compatible

// ---------------- rank (stable descending argsort) + regression -------------
__global__ __launch_bounds__(256) void rank_kernel(const float* __restrict__ scores,
                                                   const float* __restrict__ proposals,
                                                   const float* __restrict__ deltas,
                                                   int* __restrict__ order,
                                                   float* __restrict__ boxes_ws) {
    int b = blockIdx.x >> 5;
    int blk = blockIdx.x & 31;
    __shared__ float s[NN];
    const float* sb = scores + b * NN;
    for (int u = threadIdx.x; u < NN / 4; u += 256)
        ((float4*)s)[u] = ((const float4*)sb)[u];
    __syncthreads();

    int i = blk * 64 + (threadIdx.x >> 2);
    int q = threadIdx.x & 3;
    float si = (i < NN) ? s[i] : 0.f;
    int cnt = 0;
    int j0 = q * 500;
    const float4* s4 = (const float4*)s;
#pragma unroll 5
    for (int u = 0; u < 125; ++u) {
        float4 v = s4[j0 / 4 + u];
        int j = j0 + u * 4;
        cnt += (v.x > si) + (v.y > si) + (v.z > si) + (v.w > si);
        cnt += ((v.x == si) & (j + 0 < i)) + ((v.y == si) & (j + 1 < i))
             + ((v.z == si) & (j + 2 < i)) + ((v.w == si) & (j + 3 < i));
    }
    cnt += __shfl_xor(cnt, 1);
    cnt += __shfl_xor(cnt, 2);

    if (q == 0 && i < NN && cnt < K_PRE) {
        int rank = cnt;
        order[b * KPAD + rank] = i;
        const float* p = proposals + (size_t)(b * NN + i) * 6;
        const float* d = deltas    + (size_t)(b * NN + i) * 6;
        float py1 = p[0], px1 = p[1], pz1 = p[2], py2 = p[3], px2 = p[4], pz2 = p[5];
        float h = py2 - py1, w = px2 - px1, dd = pz2 - pz1;
        float cy = py1 + 0.5f * h + d[0] * h;
        float cx = px1 + 0.5f * w + d[1] * w;
        float cz = pz1 + 0.5f * dd + d[2] * dd;
        h *= expf(d[3]); w *= expf(d[4]); dd *= expf(d[5]);
        float* bw = boxes_ws + (size_t)b * 6 * KPAD + rank;
        bw[0 * KPAD] = cy - 0.5f * h;  bw[1 * KPAD] = cx - 0.5f * w;  bw[2 * KPAD] = cz - 0.5f * dd;
        bw[3 * KPAD] = cy + 0.5f * h;  bw[4 * KPAD] = cx + 0.5f * w;  bw[5 * KPAD] = cz + 0.5f * dd;
    }
}

// ---------------- suppression bit-matrix build ------------------------------
// rowBits[(b*KPAD+k)*64+l] (uint16): bit w <=> IoU(box k, box 64w+l) > thr
__global__ __launch_bounds__(256) void build_kernel(const float* __restrict__ boxes_ws,
                                                    unsigned short* __restrict__ rowBits) {
    int b = blockIdx.y;
    int kbase = blockIdx.x * 16;
    __shared__ float sbx[6][1088];     // stride-17 padding: index k + (k>>4)
    int tid = threadIdx.x;
    const float* bw = boxes_ws + (size_t)b * 6 * KPAD;
    for (int k = tid; k < KPAD; k += 256) {
        int ks = k + (k >> 4);
#pragma unroll
        for (int c = 0; c < 6; ++c) sbx[c][ks] = bw[c * KPAD + k];
    }
    __syncthreads();
    int l = tid & 63, lr = tid >> 6;
#pragma unroll
    for (int pss = 0; pss < 4; ++pss) {
        int k = kbase + pss * 4 + lr;
        int ks = k + (k >> 4);
        float ry1 = sbx[0][ks], rx1 = sbx[1][ks], rz1 = sbx[2][ks];
        float ry2 = sbx[3][ks], rx2 = sbx[4][ks], rz2 = sbx[5][ks];
        float v1 = (ry2 - ry1) * (rx2 - rx1) * (rz2 - rz1);
        uint32_t bits = 0;
#pragma unroll
        for (int w = 0; w < 16; ++w) {
            int j = 64 * w + l;
            int js = j + (j >> 4);
            float y1 = sbx[0][js], x1 = sbx[1][js], z1 = sbx[2][js];
            float y2 = sbx[3][js], x2 = sbx[4][js], z2 = sbx[5][js];
            float iy = fmaxf(fminf(ry2, y2) - fmaxf(ry1, y1), 0.f);
            float ix = fmaxf(fminf(rx2, x2) - fmaxf(rx1, x1), 0.f);
            float iz = fmaxf(fminf(rz2, z2) - fmaxf(rz1, z1), 0.f);
            float inter = iy * ix * iz;
            float v2 = (y2 - y1) * (x2 - x1) * (z2 - z1);
            float iou = inter / (v1 + v2 - inter + 1e-8f);
            bits |= (iou > NMS_THR ? 1u : 0u) << w;
        }
        if (k < K_PRE)
            rowBits[((size_t)(b * KPAD + k)) * 64 + l] = (unsigned short)bits;
    }
}

// ---------------- fused walk + chunk-lane resize (512 threads) --------------
__global__ __launch_bounds__(512) void resize_walk_kernel(
        const float* __restrict__ masks,
        const unsigned short* __restrict__ rowBits,
        const int* __restrict__ order,
        const float* __restrict__ boxes_ws,
        float* __restrict__ out_boxes,
        float* __restrict__ out_masks,
        float* __restrict__ out_bidx) {
    int s = blockIdx.x;            // 0..511
    int b = s >> 7;
    int sl = s & 127;              // which pick this block owns
    int tid = threadIdx.x;

    __shared__ int   res_k;
    __shared__ float res_vf;

    // ---- redundant early-exit ballot walk (R12/R16-proven; wave 0 only) ----
    if (tid < 64) {
        int lane = tid;
        const unsigned short* rowB = rowBits + (size_t)b * KPAD * 64;
        uint32_t sup = (lane >= 40) ? (1u << 15) : 0u;   // pads >=1000 pre-suppressed
        int nsel = 0, kmine = 0, got = 0;

        auto ROW = [&](int g) -> unsigned short {
            return rowB[((size_t)g << 6) + lane];        // L2 read, 128 B/row
        };

        for (int w = 0; w < 16 && nsel <= sl; ++w) {
            unsigned long long m = ~__ballot((int)((sup >> w) & 1u));
            while (m != 0ull && nsel <= sl) {
                unsigned long long t = m;
                int k1 = __builtin_ctzll(t); t &= t - 1;
                bool h2 = t != 0; int k2 = h2 ? __builtin_ctzll(t) : k1; t &= t - 1;
                bool h3 = t != 0; int k3 = h3 ? __builtin_ctzll(t) : k1; t &= t - 1;
                bool h4 = t != 0; int k4 = h4 ? __builtin_ctzll(t) : k1;
                int g1 = (w << 6) + k1, g2 = (w << 6) + k2;
                int g3 = (w << 6) + k3, g4 = (w << 6) + k4;
                unsigned short r1 = ROW(g1), r2 = ROW(g2), r3 = ROW(g3), r4 = ROW(g4);
                if (nsel == sl) { kmine = g1; got = 1; }
                sup |= r1; nsel++;
                m = ~__ballot((int)((sup >> w) & 1u));
                if (h2 && nsel <= sl && ((m >> k2) & 1ull)) {
                    if (nsel == sl) { kmine = g2; got = 1; }
                    sup |= r2; nsel++;
                    m = ~__ballot((int)((sup >> w) & 1u));
                }
                if (h3 && nsel <= sl && ((m >> k3) & 1ull)) {
                    if (nsel == sl) { kmine = g3; got = 1; }
                    sup |= r3; nsel++;
                    m = ~__ballot((int)((sup >> w) & 1u));
                }
                if (h4 && nsel <= sl && ((m >> k4) & 1ull)) {
                    if (nsel == sl) { kmine = g4; got = 1; }
                    sup |= r4; nsel++;
                    m = ~__ballot((int)((sup >> w) & 1u));
                }
            }
        }
        if (lane == 0) { res_k = kmine; res_vf = got ? 1.f : 0.f; }
    }
    __syncthreads();

    int k = res_k;
    float vf = res_vf;
    int gi = order[b * KPAD + k];

    if (tid == 0) {
        const float* bw = boxes_ws + (size_t)b * 6 * KPAD;
        float* ob = out_boxes + (size_t)s * 6;
#pragma unroll
        for (int c = 0; c < 6; ++c) ob[c] = bw[c * KPAD + k] * vf;
        out_bidx[s] = (float)b;
    }

    // ---- chunk-lane resize: thread = (tg, oy, ox-quad); tg covers 16 oz ----
    const float* src = masks + (size_t)(b * NN + gi) * MASK_IN_VOX;
    float* dst = out_masks + (size_t)s * MASK_OUT_VOX;

    int tg = tid >> 8;         // oz half: 0 -> oz 0..15, 1 -> oz 16..31
    int t8 = tid & 255;
    int q  = t8 & 7;           // ox quad 0..7 (ox = 4q..4q+3)
    int oy = t8 >> 3;          // 0..31

    // y taps (loop-invariant)
    int yf = (oy == 0) ? -1 : (14 * oy - 1) >> 4;
    float fy = (0.875f * (float)oy - 0.0625f) - (float)yf;
    int y0 = yf < 0 ? 0 : yf;
    int y1 = yf + 1 > 27 ? 27 : yf + 1;

    // x chunk window for this quad: chunks cA, cB cover all 8 taps
    int ox0 = q * 4;
    int xf0 = (ox0 == 0) ? -1 : (14 * ox0 - 1) >> 4;
    int x0q = xf0 < 0 ? 0 : xf0;
    int cA = x0q >> 2;
    int cB = cA + 1 > 6 ? 6 : cA + 1;

    // 4x8 x-lerp weight matrix (loop-invariant, static indices)
    float W[4][8];
#pragma unroll
    for (int qq = 0; qq < 4; ++qq) {
        int ox = ox0 + qq;
        int xf = (ox == 0) ? -1 : (14 * ox - 1) >> 4;
        float fx = (0.875f * (float)ox - 0.0625f) - (float)xf;
        int x0 = xf < 0 ? 0 : xf;
        int x1 = xf + 1 > 27 ? 27 : xf + 1;
        int i0 = x0 - (cA << 2), i1 = x1 - (cA << 2);
#pragma unroll
        for (int m = 0; m < 8; ++m)
            W[qq][m] = (m == i0 ? 1.f - fx : 0.f) + (m == i1 ? fx : 0.f);
    }

    // y-lerped windows for slices z0 (W0a,W0b) and z1 (W1a,W1b)
    f4 W0a, W0b, W1a, W1b;
    int z0c = -9, z1c = -9;

    auto YL = [&](int z, f4& wa, f4& wb) {
        const f4* r0 = (const f4*)(src + (z * 28 + y0) * 28);
        const f4* r1 = (const f4*)(src + (z * 28 + y1) * 28);
        f4 a0 = r0[cA], a1 = r0[cB];
        f4 b0 = r1[cA], b1 = r1[cB];
        wa = a0 + fy * (b0 - a0);
        wb = a1 + fy * (b1 - a1);
    };

    int oz0 = tg * 16;
    for (int oz = oz0; oz < oz0 + 16; ++oz) {
        int zf = (oz == 0) ? -1 : (14 * oz - 1) >> 4;
        float fz = (0.875f * (float)oz - 0.0625f) - (float)zf;
        int z0 = zf < 0 ? 0 : zf;
        int z1 = zf + 1 > 27 ? 27 : zf + 1;

        if (z0 != z0c) {
            if (z0 == z1c) { W0a = W1a; W0b = W1b; }
            else           { YL(z0, W0a, W0b); }
            z0c = z0;
        }
        if (z1 != z1c) { YL(z1, W1a, W1b); z1c = z1; }

        f4 Ca = W0a + fz * (W1a - W0a);
        f4 Cb = W0b + fz * (W1b - W0b);
        float e0 = Ca.x, e1 = Ca.y, e2 = Ca.z, e3 = Ca.w;
        float e4 = Cb.x, e5 = Cb.y, e6 = Cb.z, e7 = Cb.w;

        f4 o;
#pragma unroll
        for (int qq = 0; qq < 4; ++qq) {
            float acc = W[qq][0] * e0 + W[qq][1] * e1 + W[qq][2] * e2 + W[qq][3] * e3
                      + W[qq][4] * e4 + W[qq][5] * e5 + W[qq][6] * e6 + W[qq][7] * e7;
            o[qq] = acc * vf;
        }
        __builtin_nontemporal_store(o, (f4*)(dst + oz * 1024 + oy * 32 + ox0));
    }
}

// ---------------- launch ----------------------------------------------------
extern "C" void kernel_launch(void* const* d_in, const int* in_sizes, int n_in,
                              void* d_out, int out_size, void* d_ws, size_t ws_size,
                              hipStream_t stream) {
    const float* proposals = (const float*)d_in[0];
    const float* scores    = (const float*)d_in[1];
    const float* deltas    = (const float*)d_in[2];
    const float* masks     = (const float*)d_in[3];

    float* out = (float*)d_out;
    float* out_boxes = out;                                              // [512,6]
    float* out_masks = out + (size_t)BB * MAXOUT * 6;                    // [512,32768]
    float* out_bidx  = out + (size_t)BB * MAXOUT * 6 + (size_t)BB * MAXOUT * MASK_OUT_VOX;

    char* ws = (char*)d_ws;
    int*            order    = (int*)(ws);                               // 16 KB
    float*          boxes_ws = (float*)(ws + (20 << 10));                // 96 KB
    unsigned short* rowBits  = (unsigned short*)(ws + (116 << 10));      // 512 KB

    rank_kernel<<<BB * 32, 256, 0, stream>>>(scores, proposals, deltas, order, boxes_ws);
    build_kernel<<<dim3(64, BB), 256, 0, stream>>>(boxes_ws, rowBits);
    resize_walk_kernel<<<BB * MAXOUT, 512, 0, stream>>>(masks, rowBits, order, boxes_ws,
                                                        out_boxes, out_masks, out_bidx);
}

// Round 20
// 52.426 us; speedup vs baseline: 1.5618x; 1.2215x over previous
//
#include <hip/hip_runtime.h>
#include <stdint.h>

#define BB 4
#define NN 2000
#define K_PRE 1000
#define KPAD 1024
#define MAXOUT 128
#define NMS_THR 0.3f
#define MASK_IN_VOX (28*28*28)   // 21952
#define MASK_OUT_VOX (32*32*32)  // 32768

typedef float f4 __attribute__((ext_vector_type(4)));   // nontemporal-compatible

// ---------------- rank (stable descending argsort) + regression -------------
__global__ __launch_bounds__(256) void rank_kernel(const float* __restrict__ scores,
                                                   const float* __restrict__ proposals,
                                                   const float* __restrict__ deltas,
                                                   int* __restrict__ order,
                                                   float* __restrict__ boxes_ws) {
    int b = blockIdx.x >> 5;
    int blk = blockIdx.x & 31;
    __shared__ float s[NN];
    const float* sb = scores + b * NN;
    for (int u = threadIdx.x; u < NN / 4; u += 256)
        ((float4*)s)[u] = ((const float4*)sb)[u];
    __syncthreads();

    int i = blk * 64 + (threadIdx.x >> 2);
    int q = threadIdx.x & 3;
    float si = (i < NN) ? s[i] : 0.f;
    int cnt = 0;
    int j0 = q * 500;
    const float4* s4 = (const float4*)s;
#pragma unroll 5
    for (int u = 0; u < 125; ++u) {
        float4 v = s4[j0 / 4 + u];
        int j = j0 + u * 4;
        cnt += (v.x > si) + (v.y > si) + (v.z > si) + (v.w > si);
        cnt += ((v.x == si) & (j + 0 < i)) + ((v.y == si) & (j + 1 < i))
             + ((v.z == si) & (j + 2 < i)) + ((v.w == si) & (j + 3 < i));
    }
    cnt += __shfl_xor(cnt, 1);
    cnt += __shfl_xor(cnt, 2);

    if (q == 0 && i < NN && cnt < K_PRE) {
        int rank = cnt;
        order[b * KPAD + rank] = i;
        const float* p = proposals + (size_t)(b * NN + i) * 6;
        const float* d = deltas    + (size_t)(b * NN + i) * 6;
        float py1 = p[0], px1 = p[1], pz1 = p[2], py2 = p[3], px2 = p[4], pz2 = p[5];
        float h = py2 - py1, w = px2 - px1, dd = pz2 - pz1;
        float cy = py1 + 0.5f * h + d[0] * h;
        float cx = px1 + 0.5f * w + d[1] * w;
        float cz = pz1 + 0.5f * dd + d[2] * dd;
        h *= expf(d[3]); w *= expf(d[4]); dd *= expf(d[5]);
        float* bw = boxes_ws + (size_t)b * 6 * KPAD + rank;
        bw[0 * KPAD] = cy - 0.5f * h;  bw[1 * KPAD] = cx - 0.5f * w;  bw[2 * KPAD] = cz - 0.5f * dd;
        bw[3 * KPAD] = cy + 0.5f * h;  bw[4 * KPAD] = cx + 0.5f * w;  bw[5 * KPAD] = cz + 0.5f * dd;
    }
}

// ---------------- suppression bit-matrix build (paired rows) ----------------
// pairBits[(b*512+p)*64+l] (uint32): low16 = row 2p, high16 = row 2p+1;
// bit w of each half <=> IoU(box row, box 64w+l) > thr
__global__ __launch_bounds__(256) void build_kernel(const float* __restrict__ boxes_ws,
                                                    uint32_t* __restrict__ pairBits) {
    int b = blockIdx.y;
    int pbase = blockIdx.x * 8;        // 8 pairs (16 rows) per block, 64 blocks
    __shared__ float sbx[6][1088];     // stride-17 padding: index k + (k>>4)
    int tid = threadIdx.x;
    const float* bw = boxes_ws + (size_t)b * 6 * KPAD;
    for (int k = tid; k < KPAD; k += 256) {
        int ks = k + (k >> 4);
#pragma unroll
        for (int c = 0; c < 6; ++c) sbx[c][ks] = bw[c * KPAD + k];
    }
    __syncthreads();
    int l = tid & 63, lr = tid >> 6;
#pragma unroll
    for (int pss = 0; pss < 2; ++pss) {
        int p = pbase + pss * 4 + lr;
        uint32_t out = 0;
#pragma unroll
        for (int half = 0; half < 2; ++half) {
            int k = 2 * p + half;
            int ks = k + (k >> 4);
            float ry1 = sbx[0][ks], rx1 = sbx[1][ks], rz1 = sbx[2][ks];
            float ry2 = sbx[3][ks], rx2 = sbx[4][ks], rz2 = sbx[5][ks];
            float v1 = (ry2 - ry1) * (rx2 - rx1) * (rz2 - rz1);
            uint32_t bits = 0;
#pragma unroll
            for (int w = 0; w < 16; ++w) {
                int j = 64 * w + l;
                int js = j + (j >> 4);
                float y1 = sbx[0][js], x1 = sbx[1][js], z1 = sbx[2][js];
                float y2 = sbx[3][js], x2 = sbx[4][js], z2 = sbx[5][js];
                float iy = fmaxf(fminf(ry2, y2) - fmaxf(ry1, y1), 0.f);
                float ix = fmaxf(fminf(rx2, x2) - fmaxf(rx1, x1), 0.f);
                float iz = fmaxf(fminf(rz2, z2) - fmaxf(rz1, z1), 0.f);
                float inter = iy * ix * iz;
                float v2 = (y2 - y1) * (x2 - x1) * (z2 - z1);
                float iou = inter / (v1 + v2 - inter + 1e-8f);
                bits |= (iou > NMS_THR ? 1u : 0u) << w;
            }
            out |= bits << (16 * half);
        }
        if (p < K_PRE / 2)
            pairBits[((size_t)(b * 512 + p)) * 64 + l] = out;
    }
}

// ---------------- fused walk (paired, 8 cand/round) + chunk-lane resize -----
__global__ __launch_bounds__(512) void resize_walk_kernel(
        const float* __restrict__ masks,
        const uint32_t* __restrict__ pairBits,
        const int* __restrict__ order,
        const float* __restrict__ boxes_ws,
        float* __restrict__ out_boxes,
        float* __restrict__ out_masks,
        float* __restrict__ out_bidx) {
    int s = blockIdx.x;            // 0..511
    int b = s >> 7;
    int sl = s & 127;              // which pick this block owns
    int tid = threadIdx.x;

    __shared__ int   res_k;
    __shared__ float res_vf;

    // ---- redundant early-exit ballot walk, paired rows ----
    if (tid < 64) {
        int lane = tid;
        const uint32_t* pairB = pairBits + (size_t)b * 512 * 64;
        uint32_t sup = (lane >= 40) ? (1u << 15) : 0u;   // pads >=1000 pre-suppressed
        int nsel = 0, kmine = 0, got = 0;

        auto PAIR = [&](int p) -> uint32_t {
            return pairB[((size_t)p << 6) + lane];       // 256 B/pair across wave
        };

        for (int w = 0; w < 16 && nsel <= sl; ++w) {
            unsigned long long m = ~__ballot((int)((sup >> w) & 1u));
            while (m != 0ull && nsel <= sl) {
                // first 4 candidate PAIRS (each covers 2 rows)
                unsigned long long t = m;
                int p1 = __builtin_ctzll(t) >> 1; t &= ~(3ull << (p1 * 2));
                bool h2 = t != 0; int p2 = h2 ? (__builtin_ctzll(t) >> 1) : p1; t &= ~(3ull << (p2 * 2));
                bool h3 = t != 0; int p3 = h3 ? (__builtin_ctzll(t) >> 1) : p1; t &= ~(3ull << (p3 * 2));
                bool h4 = t != 0; int p4 = h4 ? (__builtin_ctzll(t) >> 1) : p1;
                uint32_t q1 = PAIR((w << 5) + p1), q2 = PAIR((w << 5) + p2);
                uint32_t q3 = PAIR((w << 5) + p3), q4 = PAIR((w << 5) + p4);

                // process rows ascending; validate each against refreshed ballot
                auto ACC = [&](uint32_t rowbits, int kbit) {
                    if (nsel <= sl && ((m >> kbit) & 1ull)) {
                        if (nsel == sl) { kmine = (w << 6) + kbit; got = 1; }
                        sup |= rowbits;
                        nsel++;
                        m = ~__ballot((int)((sup >> w) & 1u));
                    }
                };
                ACC(q1 & 0xFFFFu, 2 * p1); ACC(q1 >> 16, 2 * p1 + 1);
                if (h2) { ACC(q2 & 0xFFFFu, 2 * p2); ACC(q2 >> 16, 2 * p2 + 1); }
                if (h3) { ACC(q3 & 0xFFFFu, 2 * p3); ACC(q3 >> 16, 2 * p3 + 1); }
                if (h4) { ACC(q4 & 0xFFFFu, 2 * p4); ACC(q4 >> 16, 2 * p4 + 1); }
            }
        }
        if (lane == 0) { res_k = kmine; res_vf = got ? 1.f : 0.f; }
    }
    __syncthreads();

    int k = res_k;
    float vf = res_vf;
    int gi = order[b * KPAD + k];

    if (tid == 0) {
        const float* bw = boxes_ws + (size_t)b * 6 * KPAD;
        float* ob = out_boxes + (size_t)s * 6;
#pragma unroll
        for (int c = 0; c < 6; ++c) ob[c] = bw[c * KPAD + k] * vf;
        out_bidx[s] = (float)b;
    }

    // ---- chunk-lane resize: thread = (tg, oy, ox-quad); tg covers 16 oz ----
    const float* src = masks + (size_t)(b * NN + gi) * MASK_IN_VOX;
    float* dst = out_masks + (size_t)s * MASK_OUT_VOX;

    int tg = tid >> 8;         // oz half: 0 -> oz 0..15, 1 -> oz 16..31
    int t8 = tid & 255;
    int q  = t8 & 7;           // ox quad 0..7 (ox = 4q..4q+3)
    int oy = t8 >> 3;          // 0..31

    int yf = (oy == 0) ? -1 : (14 * oy - 1) >> 4;
    float fy = (0.875f * (float)oy - 0.0625f) - (float)yf;
    int y0 = yf < 0 ? 0 : yf;
    int y1 = yf + 1 > 27 ? 27 : yf + 1;

    int ox0 = q * 4;
    int xf0 = (ox0 == 0) ? -1 : (14 * ox0 - 1) >> 4;
    int x0q = xf0 < 0 ? 0 : xf0;
    int cA = x0q >> 2;
    int cB = cA + 1 > 6 ? 6 : cA + 1;

    float W[4][8];
#pragma unroll
    for (int qq = 0; qq < 4; ++qq) {
        int ox = ox0 + qq;
        int xf = (ox == 0) ? -1 : (14 * ox - 1) >> 4;
        float fx = (0.875f * (float)ox - 0.0625f) - (float)xf;
        int x0 = xf < 0 ? 0 : xf;
        int x1 = xf + 1 > 27 ? 27 : xf + 1;
        int i0 = x0 - (cA << 2), i1 = x1 - (cA << 2);
#pragma unroll
        for (int m = 0; m < 8; ++m)
            W[qq][m] = (m == i0 ? 1.f - fx : 0.f) + (m == i1 ? fx : 0.f);
    }

    f4 W0a, W0b, W1a, W1b;
    int z0c = -9, z1c = -9;

    auto YL = [&](int z, f4& wa, f4& wb) {
        const f4* r0 = (const f4*)(src + (z * 28 + y0) * 28);
        const f4* r1 = (const f4*)(src + (z * 28 + y1) * 28);
        f4 a0 = r0[cA], a1 = r0[cB];
        f4 b0 = r1[cA], b1 = r1[cB];
        wa = a0 + fy * (b0 - a0);
        wb = a1 + fy * (b1 - a1);
    };

    int oz0 = tg * 16;
    for (int oz = oz0; oz < oz0 + 16; ++oz) {
        int zf = (oz == 0) ? -1 : (14 * oz - 1) >> 4;
        float fz = (0.875f * (float)oz - 0.0625f) - (float)zf;
        int z0 = zf < 0 ? 0 : zf;
        int z1 = zf + 1 > 27 ? 27 : zf + 1;

        if (z0 != z0c) {
            if (z0 == z1c) { W0a = W1a; W0b = W1b; }
            else           { YL(z0, W0a, W0b); }
            z0c = z0;
        }
        if (z1 != z1c) { YL(z1, W1a, W1b); z1c = z1; }

        f4 Ca = W0a + fz * (W1a - W0a);
        f4 Cb = W0b + fz * (W1b - W0b);
        float e0 = Ca.x, e1 = Ca.y, e2 = Ca.z, e3 = Ca.w;
        float e4 = Cb.x, e5 = Cb.y, e6 = Cb.z, e7 = Cb.w;

        f4 o;
#pragma unroll
        for (int qq = 0; qq < 4; ++qq) {
            float acc = W[qq][0] * e0 + W[qq][1] * e1 + W[qq][2] * e2 + W[qq][3] * e3
                      + W[qq][4] * e4 + W[qq][5] * e5 + W[qq][6] * e6 + W[qq][7] * e7;
            o[qq] = acc * vf;
        }
        __builtin_nontemporal_store(o, (f4*)(dst + oz * 1024 + oy * 32 + ox0));
    }
}

// ---------------- launch ----------------------------------------------------
extern "C" void kernel_launch(void* const* d_in, const int* in_sizes, int n_in,
                              void* d_out, int out_size, void* d_ws, size_t ws_size,
                              hipStream_t stream) {
    const float* proposals = (const float*)d_in[0];
    const float* scores    = (const float*)d_in[1];
    const float* deltas    = (const float*)d_in[2];
    const float* masks     = (const float*)d_in[3];

    float* out = (float*)d_out;
    float* out_boxes = out;                                              // [512,6]
    float* out_masks = out + (size_t)BB * MAXOUT * 6;                    // [512,32768]
    float* out_bidx  = out + (size_t)BB * MAXOUT * 6 + (size_t)BB * MAXOUT * MASK_OUT_VOX;

    char* ws = (char*)d_ws;
    int*       order    = (int*)(ws);                                    // 16 KB
    float*     boxes_ws = (float*)(ws + (20 << 10));                     // 96 KB
    uint32_t*  pairBits = (uint32_t*)(ws + (116 << 10));                 // 512 KB

    rank_kernel<<<BB * 32, 256, 0, stream>>>(scores, proposals, deltas, order, boxes_ws);
    build_kernel<<<dim3(64, BB), 256, 0, stream>>>(boxes_ws, pairBits);
    resize_walk_kernel<<<BB * MAXOUT, 512, 0, stream>>>(masks, pairBits, order, boxes_ws,
                                                        out_boxes, out_masks, out_bidx);
}

// Round 21
// 50.022 us; speedup vs baseline: 1.6368x; 1.0481x over previous
//
#include <hip/hip_runtime.h>
#include <stdint.h>

#define BB 4
#define NN 2000
#define K_PRE 1000
#define KPAD 1024
#define MAXOUT 128
#define NMS_THR 0.3f
#define MASK_IN_VOX (28*28*28)   // 21952
#define MASK_OUT_VOX (32*32*32)  // 32768

typedef float f4 __attribute__((ext_vector_type(4)));   // nontemporal-compatible

// ---------------- rank (stable descending argsort) + regression -------------
__global__ __launch_bounds__(256) void rank_kernel(const float* __restrict__ scores,
                                                   const float* __restrict__ proposals,
                                                   const float* __restrict__ deltas,
                                                   int* __restrict__ order,
                                                   float* __restrict__ boxes_ws) {
    int b = blockIdx.x >> 5;
    int blk = blockIdx.x & 31;
    __shared__ float s[NN];
    const float* sb = scores + b * NN;
    for (int u = threadIdx.x; u < NN / 4; u += 256)
        ((float4*)s)[u] = ((const float4*)sb)[u];
    __syncthreads();

    int i = blk * 64 + (threadIdx.x >> 2);
    int q = threadIdx.x & 3;
    float si = (i < NN) ? s[i] : 0.f;
    int cnt = 0;
    int j0 = q * 500;
    const float4* s4 = (const float4*)s;
#pragma unroll 5
    for (int u = 0; u < 125; ++u) {
        float4 v = s4[j0 / 4 + u];
        int j = j0 + u * 4;
        cnt += (v.x > si) + (v.y > si) + (v.z > si) + (v.w > si);
        cnt += ((v.x == si) & (j + 0 < i)) + ((v.y == si) & (j + 1 < i))
             + ((v.z == si) & (j + 2 < i)) + ((v.w == si) & (j + 3 < i));
    }
    cnt += __shfl_xor(cnt, 1);
    cnt += __shfl_xor(cnt, 2);

    if (q == 0 && i < NN && cnt < K_PRE) {
        int rank = cnt;
        order[b * KPAD + rank] = i;
        const float* p = proposals + (size_t)(b * NN + i) * 6;
        const float* d = deltas    + (size_t)(b * NN + i) * 6;
        float py1 = p[0], px1 = p[1], pz1 = p[2], py2 = p[3], px2 = p[4], pz2 = p[5];
        float h = py2 - py1, w = px2 - px1, dd = pz2 - pz1;
        float cy = py1 + 0.5f * h + d[0] * h;
        float cx = px1 + 0.5f * w + d[1] * w;
        float cz = pz1 + 0.5f * dd + d[2] * dd;
        h *= expf(d[3]); w *= expf(d[4]); dd *= expf(d[5]);
        float* bw = boxes_ws + (size_t)b * 6 * KPAD + rank;
        bw[0 * KPAD] = cy - 0.5f * h;  bw[1 * KPAD] = cx - 0.5f * w;  bw[2 * KPAD] = cz - 0.5f * dd;
        bw[3 * KPAD] = cy + 0.5f * h;  bw[4 * KPAD] = cx + 0.5f * w;  bw[5 * KPAD] = cz + 0.5f * dd;
    }
}

// ---------------- suppression bit-matrix build (quad rows) ------------------
// quadBits[(b*256+p)*64+l] (uint64): bits [16h..16h+15] = row 4p+h's window
// bits; bit w of each 16-bit half <=> IoU(box 4p+h, box 64w+l) > thr
__global__ __launch_bounds__(256) void build_kernel(const float* __restrict__ boxes_ws,
                                                    unsigned long long* __restrict__ quadBits) {
    int b = blockIdx.y;
    int pbase = blockIdx.x * 4;        // 4 quads (16 rows) per block, 64 blocks
    __shared__ float sbx[6][1088];     // stride-17 padding: index k + (k>>4)
    int tid = threadIdx.x;
    const float* bw = boxes_ws + (size_t)b * 6 * KPAD;
    for (int k = tid; k < KPAD; k += 256) {
        int ks = k + (k >> 4);
#pragma unroll
        for (int c = 0; c < 6; ++c) sbx[c][ks] = bw[c * KPAD + k];
    }
    __syncthreads();
    int l = tid & 63, lr = tid >> 6;
    int p = pbase + lr;                // one quad per wave
    unsigned long long out = 0;
#pragma unroll
    for (int half = 0; half < 4; ++half) {
        int k = 4 * p + half;
        int ks = k + (k >> 4);
        float ry1 = sbx[0][ks], rx1 = sbx[1][ks], rz1 = sbx[2][ks];
        float ry2 = sbx[3][ks], rx2 = sbx[4][ks], rz2 = sbx[5][ks];
        float v1 = (ry2 - ry1) * (rx2 - rx1) * (rz2 - rz1);
        unsigned long long bits = 0;
#pragma unroll
        for (int w = 0; w < 16; ++w) {
            int j = 64 * w + l;
            int js = j + (j >> 4);
            float y1 = sbx[0][js], x1 = sbx[1][js], z1 = sbx[2][js];
            float y2 = sbx[3][js], x2 = sbx[4][js], z2 = sbx[5][js];
            float iy = fmaxf(fminf(ry2, y2) - fmaxf(ry1, y1), 0.f);
            float ix = fmaxf(fminf(rx2, x2) - fmaxf(rx1, x1), 0.f);
            float iz = fmaxf(fminf(rz2, z2) - fmaxf(rz1, z1), 0.f);
            float inter = iy * ix * iz;
            float v2 = (y2 - y1) * (x2 - x1) * (z2 - z1);
            float iou = inter / (v1 + v2 - inter + 1e-8f);
            bits |= (unsigned long long)(iou > NMS_THR ? 1u : 0u) << w;
        }
        out |= bits << (16 * half);
    }
    if (p < K_PRE / 4)                 // quads 250..255 are all-pad: never written
        quadBits[((size_t)(b * 256 + p)) * 64 + l] = out;
}

// ---------------- fused walk (quad, 16 cand/round) + chunk-lane resize ------
__global__ __launch_bounds__(512) void resize_walk_kernel(
        const float* __restrict__ masks,
        const unsigned long long* __restrict__ quadBits,
        const int* __restrict__ order,
        const float* __restrict__ boxes_ws,
        float* __restrict__ out_boxes,
        float* __restrict__ out_masks,
        float* __restrict__ out_bidx) {
    int s = blockIdx.x;            // 0..511
    int b = s >> 7;
    int sl = s & 127;              // which pick this block owns
    int tid = threadIdx.x;

    __shared__ int   res_k;
    __shared__ float res_vf;

    // ---- redundant early-exit walk: quad loads + parallel ballots + SALU ---
    if (tid < 64) {
        int lane = tid;
        const unsigned long long* quadB = quadBits + (size_t)b * 256 * 64;
        uint32_t sup = (lane >= 40) ? (1u << 15) : 0u;   // pads >=1000 pre-suppressed
        int nsel = 0, kmine = 0, got = 0;

        for (int w = 0; w < 16 && nsel <= sl; ++w) {
            unsigned long long m = ~__ballot((int)((sup >> w) & 1u));
            while (m != 0ull && nsel <= sl) {
                unsigned long long t = m;
                int p1 = __builtin_ctzll(t) >> 2; t &= ~(0xFull << (p1 * 4));
                bool h2 = t != 0; int p2 = h2 ? (__builtin_ctzll(t) >> 2) : p1; t &= ~(0xFull << (p2 * 4));
                bool h3 = t != 0; int p3 = h3 ? (__builtin_ctzll(t) >> 2) : p1; t &= ~(0xFull << (p3 * 4));
                bool h4 = t != 0; int p4 = h4 ? (__builtin_ctzll(t) >> 2) : p1;
                unsigned long long Q1 = quadB[(((size_t)(w << 4) + p1) << 6) + lane];
                unsigned long long Q2 = quadB[(((size_t)(w << 4) + p2) << 6) + lane];
                unsigned long long Q3 = quadB[(((size_t)(w << 4) + p3) << 6) + lane];
                unsigned long long Q4 = quadB[(((size_t)(w << 4) + p4) << 6) + lane];

#define DOQUAD(P, Q)                                                            \
                {                                                               \
                    uint32_t r0 = (uint32_t)(Q) & 0xFFFFu;                      \
                    uint32_t r1 = (uint32_t)((Q) >> 16) & 0xFFFFu;              \
                    uint32_t r2 = (uint32_t)((Q) >> 32) & 0xFFFFu;              \
                    uint32_t r3 = (uint32_t)((Q) >> 48) & 0xFFFFu;              \
                    unsigned long long b0 = __ballot((int)((r0 >> w) & 1u));    \
                    unsigned long long b1 = __ballot((int)((r1 >> w) & 1u));    \
                    unsigned long long b2 = __ballot((int)((r2 >> w) & 1u));    \
                    unsigned long long b3 = __ballot((int)((r3 >> w) & 1u));    \
                    int kb = (P) * 4;                                           \
                    if (nsel <= sl && ((m >> kb) & 1ull)) {                     \
                        if (nsel == sl) { kmine = (w << 6) + kb; got = 1; }     \
                        sup |= r0; nsel++; m &= ~b0;                            \
                    }                                                           \
                    if (nsel <= sl && ((m >> (kb + 1)) & 1ull)) {               \
                        if (nsel == sl) { kmine = (w << 6) + kb + 1; got = 1; } \
                        sup |= r1; nsel++; m &= ~b1;                            \
                    }                                                           \
                    if (nsel <= sl && ((m >> (kb + 2)) & 1ull)) {               \
                        if (nsel == sl) { kmine = (w << 6) + kb + 2; got = 1; } \
                        sup |= r2; nsel++; m &= ~b2;                            \
                    }                                                           \
                    if (nsel <= sl && ((m >> (kb + 3)) & 1ull)) {               \
                        if (nsel == sl) { kmine = (w << 6) + kb + 3; got = 1; } \
                        sup |= r3; nsel++; m &= ~b3;                            \
                    }                                                           \
                }

                DOQUAD(p1, Q1)
                if (h2) DOQUAD(p2, Q2)
                if (h3) DOQUAD(p3, Q3)
                if (h4) DOQUAD(p4, Q4)
#undef DOQUAD
            }
        }
        if (lane == 0) { res_k = kmine; res_vf = got ? 1.f : 0.f; }
    }
    __syncthreads();

    int k = res_k;
    float vf = res_vf;
    int gi = order[b * KPAD + k];

    if (tid == 0) {
        const float* bw = boxes_ws + (size_t)b * 6 * KPAD;
        float* ob = out_boxes + (size_t)s * 6;
#pragma unroll
        for (int c = 0; c < 6; ++c) ob[c] = bw[c * KPAD + k] * vf;
        out_bidx[s] = (float)b;
    }

    // ---- chunk-lane resize: thread = (tg, oy, ox-quad); tg covers 16 oz ----
    const float* src = masks + (size_t)(b * NN + gi) * MASK_IN_VOX;
    float* dst = out_masks + (size_t)s * MASK_OUT_VOX;

    int tg = tid >> 8;         // oz half: 0 -> oz 0..15, 1 -> oz 16..31
    int t8 = tid & 255;
    int q  = t8 & 7;           // ox quad 0..7 (ox = 4q..4q+3)
    int oy = t8 >> 3;          // 0..31

    int yf = (oy == 0) ? -1 : (14 * oy - 1) >> 4;
    float fy = (0.875f * (float)oy - 0.0625f) - (float)yf;
    int y0 = yf < 0 ? 0 : yf;
    int y1 = yf + 1 > 27 ? 27 : yf + 1;

    int ox0 = q * 4;
    int xf0 = (ox0 == 0) ? -1 : (14 * ox0 - 1) >> 4;
    int x0q = xf0 < 0 ? 0 : xf0;
    int cA = x0q >> 2;
    int cB = cA + 1 > 6 ? 6 : cA + 1;

    float W[4][8];
#pragma unroll
    for (int qq = 0; qq < 4; ++qq) {
        int ox = ox0 + qq;
        int xf = (ox == 0) ? -1 : (14 * ox - 1) >> 4;
        float fx = (0.875f * (float)ox - 0.0625f) - (float)xf;
        int x0 = xf < 0 ? 0 : xf;
        int x1 = xf + 1 > 27 ? 27 : xf + 1;
        int i0 = x0 - (cA << 2), i1 = x1 - (cA << 2);
#pragma unroll
        for (int m = 0; m < 8; ++m)
            W[qq][m] = (m == i0 ? 1.f - fx : 0.f) + (m == i1 ? fx : 0.f);
    }

    f4 W0a, W0b, W1a, W1b;
    int z0c = -9, z1c = -9;

    auto YL = [&](int z, f4& wa, f4& wb) {
        const f4* r0 = (const f4*)(src + (z * 28 + y0) * 28);
        const f4* r1 = (const f4*)(src + (z * 28 + y1) * 28);
        f4 a0 = r0[cA], a1 = r0[cB];
        f4 b0 = r1[cA], b1 = r1[cB];
        wa = a0 + fy * (b0 - a0);
        wb = a1 + fy * (b1 - a1);
    };

    int oz0 = tg * 16;
    for (int oz = oz0; oz < oz0 + 16; ++oz) {
        int zf = (oz == 0) ? -1 : (14 * oz - 1) >> 4;
        float fz = (0.875f * (float)oz - 0.0625f) - (float)zf;
        int z0 = zf < 0 ? 0 : zf;
        int z1 = zf + 1 > 27 ? 27 : zf + 1;

        if (z0 != z0c) {
            if (z0 == z1c) { W0a = W1a; W0b = W1b; }
            else           { YL(z0, W0a, W0b); }
            z0c = z0;
        }
        if (z1 != z1c) { YL(z1, W1a, W1b); z1c = z1; }

        f4 Ca = W0a + fz * (W1a - W0a);
        f4 Cb = W0b + fz * (W1b - W0b);
        float e0 = Ca.x, e1 = Ca.y, e2 = Ca.z, e3 = Ca.w;
        float e4 = Cb.x, e5 = Cb.y, e6 = Cb.z, e7 = Cb.w;

        f4 o;
#pragma unroll
        for (int qq = 0; qq < 4; ++qq) {
            float acc = W[qq][0] * e0 + W[qq][1] * e1 + W[qq][2] * e2 + W[qq][3] * e3
                      + W[qq][4] * e4 + W[qq][5] * e5 + W[qq][6] * e6 + W[qq][7] * e7;
            o[qq] = acc * vf;
        }
        __builtin_nontemporal_store(o, (f4*)(dst + oz * 1024 + oy * 32 + ox0));
    }
}

// ---------------- launch ----------------------------------------------------
extern "C" void kernel_launch(void* const* d_in, const int* in_sizes, int n_in,
                              void* d_out, int out_size, void* d_ws, size_t ws_size,
                              hipStream_t stream) {
    const float* proposals = (const float*)d_in[0];
    const float* scores    = (const float*)d_in[1];
    const float* deltas    = (const float*)d_in[2];
    const float* masks     = (const float*)d_in[3];

    float* out = (float*)d_out;
    float* out_boxes = out;                                              // [512,6]
    float* out_masks = out + (size_t)BB * MAXOUT * 6;                    // [512,32768]
    float* out_bidx  = out + (size_t)BB * MAXOUT * 6 + (size_t)BB * MAXOUT * MASK_OUT_VOX;

    char* ws = (char*)d_ws;
    int*                 order    = (int*)(ws);                          // 16 KB
    float*               boxes_ws = (float*)(ws + (20 << 10));           // 96 KB
    unsigned long long*  quadBits = (unsigned long long*)(ws + (116 << 10)); // 512 KB

    rank_kernel<<<BB * 32, 256, 0, stream>>>(scores, proposals, deltas, order, boxes_ws);
    build_kernel<<<dim3(64, BB), 256, 0, stream>>>(boxes_ws, quadBits);
    resize_walk_kernel<<<BB * MAXOUT, 512, 0, stream>>>(masks, quadBits, order, boxes_ws,
                                                        out_boxes, out_masks, out_bidx);
}

// Round 22
// 49.871 us; speedup vs baseline: 1.6418x; 1.0030x over previous
//
#include <hip/hip_runtime.h>
#include <stdint.h>

#define BB 4
#define NN 2000
#define K_PRE 1000
#define KPAD 1024
#define MAXOUT 128
#define NMS_THR 0.3f
#define MASK_IN_VOX (28*28*28)   // 21952
#define MASK_OUT_VOX (32*32*32)  // 32768

typedef float f4 __attribute__((ext_vector_type(4)));   // nontemporal-compatible

// ---------------- rank (stable descending argsort) + regression -------------
__global__ __launch_bounds__(256) void rank_kernel(const float* __restrict__ scores,
                                                   const float* __restrict__ proposals,
                                                   const float* __restrict__ deltas,
                                                   int* __restrict__ order,
                                                   float* __restrict__ boxes_ws) {
    int b = blockIdx.x >> 5;
    int blk = blockIdx.x & 31;
    __shared__ float s[NN];
    const float* sb = scores + b * NN;
    for (int u = threadIdx.x; u < NN / 4; u += 256)
        ((float4*)s)[u] = ((const float4*)sb)[u];
    __syncthreads();

    int i = blk * 64 + (threadIdx.x >> 2);
    int q = threadIdx.x & 3;
    float si = (i < NN) ? s[i] : 0.f;
    int cnt = 0;
    int j0 = q * 500;
    const float4* s4 = (const float4*)s;
#pragma unroll 5
    for (int u = 0; u < 125; ++u) {
        float4 v = s4[j0 / 4 + u];
        int j = j0 + u * 4;
        cnt += (v.x > si) + (v.y > si) + (v.z > si) + (v.w > si);
        cnt += ((v.x == si) & (j + 0 < i)) + ((v.y == si) & (j + 1 < i))
             + ((v.z == si) & (j + 2 < i)) + ((v.w == si) & (j + 3 < i));
    }
    cnt += __shfl_xor(cnt, 1);
    cnt += __shfl_xor(cnt, 2);

    if (q == 0 && i < NN && cnt < K_PRE) {
        int rank = cnt;
        order[b * KPAD + rank] = i;
        const float* p = proposals + (size_t)(b * NN + i) * 6;
        const float* d = deltas    + (size_t)(b * NN + i) * 6;
        float py1 = p[0], px1 = p[1], pz1 = p[2], py2 = p[3], px2 = p[4], pz2 = p[5];
        float h = py2 - py1, w = px2 - px1, dd = pz2 - pz1;
        float cy = py1 + 0.5f * h + d[0] * h;
        float cx = px1 + 0.5f * w + d[1] * w;
        float cz = pz1 + 0.5f * dd + d[2] * dd;
        h *= expf(d[3]); w *= expf(d[4]); dd *= expf(d[5]);
        float* bw = boxes_ws + (size_t)b * 6 * KPAD + rank;
        bw[0 * KPAD] = cy - 0.5f * h;  bw[1 * KPAD] = cx - 0.5f * w;  bw[2 * KPAD] = cz - 0.5f * dd;
        bw[3 * KPAD] = cy + 0.5f * h;  bw[4 * KPAD] = cx + 0.5f * w;  bw[5 * KPAD] = cz + 0.5f * dd;
    }
}

// ---------------- suppression bit-matrix build (quad rows) ------------------
// quadBits[(b*256+p)*64+l] (uint64): bits [16h..16h+15] = row 4p+h's window
// bits; bit w of each 16-bit half <=> IoU(box 4p+h, box 64w+l) > thr
__global__ __launch_bounds__(256) void build_kernel(const float* __restrict__ boxes_ws,
                                                    unsigned long long* __restrict__ quadBits) {
    int b = blockIdx.y;
    int pbase = blockIdx.x * 4;        // 4 quads (16 rows) per block, 64 blocks
    __shared__ float sbx[6][1088];     // stride-17 padding: index k + (k>>4)
    int tid = threadIdx.x;
    const float* bw = boxes_ws + (size_t)b * 6 * KPAD;
    for (int k = tid; k < KPAD; k += 256) {
        int ks = k + (k >> 4);
#pragma unroll
        for (int c = 0; c < 6; ++c) sbx[c][ks] = bw[c * KPAD + k];
    }
    __syncthreads();
    int l = tid & 63, lr = tid >> 6;
    int p = pbase + lr;                // one quad per wave
    unsigned long long out = 0;
#pragma unroll
    for (int half = 0; half < 4; ++half) {
        int k = 4 * p + half;
        int ks = k + (k >> 4);
        float ry1 = sbx[0][ks], rx1 = sbx[1][ks], rz1 = sbx[2][ks];
        float ry2 = sbx[3][ks], rx2 = sbx[4][ks], rz2 = sbx[5][ks];
        float v1 = (ry2 - ry1) * (rx2 - rx1) * (rz2 - rz1);
        unsigned long long bits = 0;
#pragma unroll
        for (int w = 0; w < 16; ++w) {
            int j = 64 * w + l;
            int js = j + (j >> 4);
            float y1 = sbx[0][js], x1 = sbx[1][js], z1 = sbx[2][js];
            float y2 = sbx[3][js], x2 = sbx[4][js], z2 = sbx[5][js];
            float iy = fmaxf(fminf(ry2, y2) - fmaxf(ry1, y1), 0.f);
            float ix = fmaxf(fminf(rx2, x2) - fmaxf(rx1, x1), 0.f);
            float iz = fmaxf(fminf(rz2, z2) - fmaxf(rz1, z1), 0.f);
            float inter = iy * ix * iz;
            float v2 = (y2 - y1) * (x2 - x1) * (z2 - z1);
            float iou = inter / (v1 + v2 - inter + 1e-8f);
            bits |= (unsigned long long)(iou > NMS_THR ? 1u : 0u) << w;
        }
        out |= bits << (16 * half);
    }
    if (p < K_PRE / 4)                 // quads 250..255 are all-pad: never written
        quadBits[((size_t)(b * 256 + p)) * 64 + l] = out;
}

// ---------------- fused walk (quad, 32 cand/round) + chunk-lane resize ------
__global__ __launch_bounds__(512) void resize_walk_kernel(
        const float* __restrict__ masks,
        const unsigned long long* __restrict__ quadBits,
        const int* __restrict__ order,
        const float* __restrict__ boxes_ws,
        float* __restrict__ out_boxes,
        float* __restrict__ out_masks,
        float* __restrict__ out_bidx) {
    int s = blockIdx.x;            // 0..511
    int b = s >> 7;
    int sl = s & 127;              // which pick this block owns
    int tid = threadIdx.x;

    __shared__ int   res_k;
    __shared__ float res_vf;

    // ---- redundant early-exit walk: 8-quad prefetch + parallel ballots -----
    if (tid < 64) {
        int lane = tid;
        const unsigned long long* quadB = quadBits + (size_t)b * 256 * 64;
        uint32_t sup = (lane >= 40) ? (1u << 15) : 0u;   // pads >=1000 pre-suppressed
        int nsel = 0, kmine = 0, got = 0;

        for (int w = 0; w < 16 && nsel <= sl; ++w) {
            unsigned long long m = ~__ballot((int)((sup >> w) & 1u));
            while (m != 0ull && nsel <= sl) {
                // extract up to 8 candidate quads (fully unrolled, static idx)
                unsigned long long t = m;
                int  pa[8];
                bool ha[8];
#pragma unroll
                for (int e = 0; e < 8; ++e) {
                    ha[e] = (t != 0ull);
                    int pe = ha[e] ? (__builtin_ctzll(t) >> 2) : 0;
                    pa[e] = pe;
                    t &= ~(0xFull << (pe * 4));
                }
                // issue all 8 loads (independent -> MLP)
                unsigned long long Q[8];
#pragma unroll
                for (int e = 0; e < 8; ++e)
                    Q[e] = quadB[(((size_t)(w << 4) + pa[e]) << 6) + lane];

#define DOQUAD(P, QV)                                                           \
                {                                                               \
                    uint32_t r0 = (uint32_t)(QV) & 0xFFFFu;                     \
                    uint32_t r1 = (uint32_t)((QV) >> 16) & 0xFFFFu;             \
                    uint32_t r2 = (uint32_t)((QV) >> 32) & 0xFFFFu;             \
                    uint32_t r3 = (uint32_t)((QV) >> 48) & 0xFFFFu;             \
                    unsigned long long b0 = __ballot((int)((r0 >> w) & 1u));    \
                    unsigned long long b1 = __ballot((int)((r1 >> w) & 1u));    \
                    unsigned long long b2 = __ballot((int)((r2 >> w) & 1u));    \
                    unsigned long long b3 = __ballot((int)((r3 >> w) & 1u));    \
                    int kb = (P) * 4;                                           \
                    if (nsel <= sl && ((m >> kb) & 1ull)) {                     \
                        if (nsel == sl) { kmine = (w << 6) + kb; got = 1; }     \
                        sup |= r0; nsel++; m &= ~b0;                            \
                    }                                                           \
                    if (nsel <= sl && ((m >> (kb + 1)) & 1ull)) {               \
                        if (nsel == sl) { kmine = (w << 6) + kb + 1; got = 1; } \
                        sup |= r1; nsel++; m &= ~b1;                            \
                    }                                                           \
                    if (nsel <= sl && ((m >> (kb + 2)) & 1ull)) {               \
                        if (nsel == sl) { kmine = (w << 6) + kb + 2; got = 1; } \
                        sup |= r2; nsel++; m &= ~b2;                            \
                    }                                                           \
                    if (nsel <= sl && ((m >> (kb + 3)) & 1ull)) {               \
                        if (nsel == sl) { kmine = (w << 6) + kb + 3; got = 1; } \
                        sup |= r3; nsel++; m &= ~b3;                            \
                    }                                                           \
                }

                DOQUAD(pa[0], Q[0])
                if (ha[1]) DOQUAD(pa[1], Q[1])
                if (ha[2]) DOQUAD(pa[2], Q[2])
                if (ha[3]) DOQUAD(pa[3], Q[3])
                if (ha[4]) DOQUAD(pa[4], Q[4])
                if (ha[5]) DOQUAD(pa[5], Q[5])
                if (ha[6]) DOQUAD(pa[6], Q[6])
                if (ha[7]) DOQUAD(pa[7], Q[7])
#undef DOQUAD
            }
        }
        if (lane == 0) { res_k = kmine; res_vf = got ? 1.f : 0.f; }
    }
    __syncthreads();

    int k = res_k;
    float vf = res_vf;
    int gi = order[b * KPAD + k];

    if (tid == 0) {
        const float* bw = boxes_ws + (size_t)b * 6 * KPAD;
        float* ob = out_boxes + (size_t)s * 6;
#pragma unroll
        for (int c = 0; c < 6; ++c) ob[c] = bw[c * KPAD + k] * vf;
        out_bidx[s] = (float)b;
    }

    // ---- chunk-lane resize: thread = (tg, oy, ox-quad); tg covers 16 oz ----
    const float* src = masks + (size_t)(b * NN + gi) * MASK_IN_VOX;
    float* dst = out_masks + (size_t)s * MASK_OUT_VOX;

    int tg = tid >> 8;         // oz half: 0 -> oz 0..15, 1 -> oz 16..31
    int t8 = tid & 255;
    int q  = t8 & 7;           // ox quad 0..7 (ox = 4q..4q+3)
    int oy = t8 >> 3;          // 0..31

    int yf = (oy == 0) ? -1 : (14 * oy - 1) >> 4;
    float fy = (0.875f * (float)oy - 0.0625f) - (float)yf;
    int y0 = yf < 0 ? 0 : yf;
    int y1 = yf + 1 > 27 ? 27 : yf + 1;

    int ox0 = q * 4;
    int xf0 = (ox0 == 0) ? -1 : (14 * ox0 - 1) >> 4;
    int x0q = xf0 < 0 ? 0 : xf0;
    int cA = x0q >> 2;
    int cB = cA + 1 > 6 ? 6 : cA + 1;

    float W[4][8];
#pragma unroll
    for (int qq = 0; qq < 4; ++qq) {
        int ox = ox0 + qq;
        int xf = (ox == 0) ? -1 : (14 * ox - 1) >> 4;
        float fx = (0.875f * (float)ox - 0.0625f) - (float)xf;
        int x0 = xf < 0 ? 0 : xf;
        int x1 = xf + 1 > 27 ? 27 : xf + 1;
        int i0 = x0 - (cA << 2), i1 = x1 - (cA << 2);
#pragma unroll
        for (int m = 0; m < 8; ++m)
            W[qq][m] = (m == i0 ? 1.f - fx : 0.f) + (m == i1 ? fx : 0.f);
    }

    f4 W0a, W0b, W1a, W1b;
    int z0c = -9, z1c = -9;

    auto YL = [&](int z, f4& wa, f4& wb) {
        const f4* r0 = (const f4*)(src + (z * 28 + y0) * 28);
        const f4* r1 = (const f4*)(src + (z * 28 + y1) * 28);
        f4 a0 = r0[cA], a1 = r0[cB];
        f4 b0 = r1[cA], b1 = r1[cB];
        wa = a0 + fy * (b0 - a0);
        wb = a1 + fy * (b1 - a1);
    };

    int oz0 = tg * 16;
    for (int oz = oz0; oz < oz0 + 16; ++oz) {
        int zf = (oz == 0) ? -1 : (14 * oz - 1) >> 4;
        float fz = (0.875f * (float)oz - 0.0625f) - (float)zf;
        int z0 = zf < 0 ? 0 : zf;
        int z1 = zf + 1 > 27 ? 27 : zf + 1;

        if (z0 != z0c) {
            if (z0 == z1c) { W0a = W1a; W0b = W1b; }
            else           { YL(z0, W0a, W0b); }
            z0c = z0;
        }
        if (z1 != z1c) { YL(z1, W1a, W1b); z1c = z1; }

        f4 Ca = W0a + fz * (W1a - W0a);
        f4 Cb = W0b + fz * (W1b - W0b);
        float e0 = Ca.x, e1 = Ca.y, e2 = Ca.z, e3 = Ca.w;
        float e4 = Cb.x, e5 = Cb.y, e6 = Cb.z, e7 = Cb.w;

        f4 o;
#pragma unroll
        for (int qq = 0; qq < 4; ++qq) {
            float acc = W[qq][0] * e0 + W[qq][1] * e1 + W[qq][2] * e2 + W[qq][3] * e3
                      + W[qq][4] * e4 + W[qq][5] * e5 + W[qq][6] * e6 + W[qq][7] * e7;
            o[qq] = acc * vf;
        }
        __builtin_nontemporal_store(o, (f4*)(dst + oz * 1024 + oy * 32 + ox0));
    }
}

// ---------------- launch ----------------------------------------------------
extern "C" void kernel_launch(void* const* d_in, const int* in_sizes, int n_in,
                              void* d_out, int out_size, void* d_ws, size_t ws_size,
                              hipStream_t stream) {
    const float* proposals = (const float*)d_in[0];
    const float* scores    = (const float*)d_in[1];
    const float* deltas    = (const float*)d_in[2];
    const float* masks     = (const float*)d_in[3];

    float* out = (float*)d_out;
    float* out_boxes = out;                                              // [512,6]
    float* out_masks = out + (size_t)BB * MAXOUT * 6;                    // [512,32768]
    float* out_bidx  = out + (size_t)BB * MAXOUT * 6 + (size_t)BB * MAXOUT * MASK_OUT_VOX;

    char* ws = (char*)d_ws;
    int*                 order    = (int*)(ws);                          // 16 KB
    float*               boxes_ws = (float*)(ws + (20 << 10));           // 96 KB
    unsigned long long*  quadBits = (unsigned long long*)(ws + (116 << 10)); // 512 KB

    rank_kernel<<<BB * 32, 256, 0, stream>>>(scores, proposals, deltas, order, boxes_ws);
    build_kernel<<<dim3(64, BB), 256, 0, stream>>>(boxes_ws, quadBits);
    resize_walk_kernel<<<BB * MAXOUT, 512, 0, stream>>>(masks, quadBits, order, boxes_ws,
                                                        out_boxes, out_masks, out_bidx);
}